// Round 1
// baseline (681.333 us; speedup 1.0000x reference)
//
#include <hip/hip_runtime.h>
#include <hip/hip_bf16.h>
#include <stdint.h>

#define B_ 2
#define T_ 2048
#define D_ 2048
#define NH_ 16
#define NKV_ 4
#define HD_ 128
#define EQ_ (NH_*HD_)    // 2048
#define EKV_ (NKV_*HD_)  // 512

typedef __attribute__((ext_vector_type(8))) short short8;
typedef __attribute__((ext_vector_type(4))) float floatx4;

static __device__ __forceinline__ ushort f2bf(float f) {
  uint u = __builtin_bit_cast(uint, f);
  u = (u + 0x7fffu + ((u >> 16) & 1u)) >> 16;
  return (ushort)u;
}
static __device__ __forceinline__ float bf2f(ushort u) {
  return __builtin_bit_cast(float, ((uint)u) << 16);
}

// ---------------- fp32 -> bf16 convert ----------------
__global__ __launch_bounds__(256) void cvt_k(const float* __restrict__ in,
                                             ushort* __restrict__ out, int n) {
  int i = (blockIdx.x * 256 + threadIdx.x) * 2;
  if (i < n) {
    float2 f = *(const float2*)&in[i];
    ushort2 u;
    u.x = f2bf(f.x);
    u.y = f2bf(f.y);
    *(ushort2*)&out[i] = u;
  }
}

// ---------------- RMSNorm (fp32 in, bf16 out) ----------------
__global__ __launch_bounds__(256) void rmsnorm_k(const float* __restrict__ x,
                                                 const float* __restrict__ wn,
                                                 ushort* __restrict__ hb) {
  const int row = blockIdx.x, tid = threadIdx.x;
  const int w = tid >> 6, lane = tid & 63;
  const float* xr = x + (size_t)row * D_;
  float v[8];
  float4 a = *(const float4*)&xr[tid * 8];
  float4 b = *(const float4*)&xr[tid * 8 + 4];
  v[0] = a.x; v[1] = a.y; v[2] = a.z; v[3] = a.w;
  v[4] = b.x; v[5] = b.y; v[6] = b.z; v[7] = b.w;
  float ss = 0.f;
#pragma unroll
  for (int i = 0; i < 8; i++) ss += v[i] * v[i];
  for (int m = 32; m; m >>= 1) ss += __shfl_xor(ss, m);
  __shared__ float red[4];
  if (lane == 0) red[w] = ss;
  __syncthreads();
  float tot = red[0] + red[1] + red[2] + red[3];
  float sc = rsqrtf(tot * (1.f / D_) + 1e-6f);
  short8 st;
#pragma unroll
  for (int i = 0; i < 8; i++) st[i] = (short)f2bf(v[i] * sc * wn[tid * 8 + i]);
  *(short8*)(hb + (size_t)row * D_ + tid * 8) = st;
}

// ---------------- GEMM: C[M][N] = A[M][K] * W[N][K]^T (bf16 in, f32 acc) ---
template <bool OUT_F32>
__global__ __launch_bounds__(256) void gemm_bt(const ushort* __restrict__ A,
                                               const ushort* __restrict__ W,
                                               void* __restrict__ Cp,
                                               int M, int N, int K) {
  __shared__ __align__(16) ushort lA[128 * 32];
  __shared__ __align__(16) ushort lB[128 * 32];
  const int tid = threadIdx.x;
  const int w = tid >> 6, lane = tid & 63;
  const int bm = blockIdx.y, bn = blockIdx.x;
  const int wm = w >> 1, wn = w & 1;
  const int l15 = lane & 15, l4 = lane >> 4;

  floatx4 acc[4][4];
#pragma unroll
  for (int m = 0; m < 4; m++)
#pragma unroll
    for (int n = 0; n < 4; n++) acc[m][n] = floatx4{0.f, 0.f, 0.f, 0.f};

  for (int k0 = 0; k0 < K; k0 += 32) {
    // stage A and B tiles, 16B per lane via global_load_lds
#pragma unroll
    for (int r = 0; r < 2; ++r) {
      int c = w * 128 + r * 64 + lane;
      const ushort* ga = A + (size_t)(bm * 128 + (c >> 2)) * K + k0 + (c & 3) * 8;
      __builtin_amdgcn_global_load_lds(
          (const __attribute__((address_space(1))) void*)ga,
          (__attribute__((address_space(3))) void*)&lA[c * 8], 16, 0, 0);
      const ushort* gb = W + (size_t)(bn * 128 + (c >> 2)) * K + k0 + (c & 3) * 8;
      __builtin_amdgcn_global_load_lds(
          (const __attribute__((address_space(1))) void*)gb,
          (__attribute__((address_space(3))) void*)&lB[c * 8], 16, 0, 0);
    }
    __syncthreads();
#pragma unroll
    for (int m = 0; m < 4; m++) {
      short8 a = *(const short8*)&lA[(wm * 64 + m * 16 + l15) * 32 + l4 * 8];
#pragma unroll
      for (int n = 0; n < 4; n++) {
        short8 b = *(const short8*)&lB[(wn * 64 + n * 16 + l15) * 32 + l4 * 8];
        acc[m][n] = __builtin_amdgcn_mfma_f32_16x16x32_bf16(a, b, acc[m][n], 0, 0, 0);
      }
    }
    __syncthreads();
  }

  if (OUT_F32) {
    float* C = (float*)Cp;
#pragma unroll
    for (int m = 0; m < 4; m++)
#pragma unroll
      for (int n = 0; n < 4; n++)
#pragma unroll
        for (int j = 0; j < 4; j++) {
          int row = bm * 128 + wm * 64 + m * 16 + l4 * 4 + j;
          int col = bn * 128 + wn * 64 + n * 16 + l15;
          C[(size_t)row * N + col] = acc[m][n][j];
        }
  } else {
    ushort* C = (ushort*)Cp;
#pragma unroll
    for (int m = 0; m < 4; m++)
#pragma unroll
      for (int n = 0; n < 4; n++)
#pragma unroll
        for (int j = 0; j < 4; j++) {
          int row = bm * 128 + wm * 64 + m * 16 + l4 * 4 + j;
          int col = bn * 128 + wn * 64 + n * 16 + l15;
          C[(size_t)row * N + col] = f2bf(acc[m][n][j]);
        }
  }
}

// ---------------- partial RoPE (in-place on bf16) ----------------
__global__ __launch_bounds__(256) void rope_k(ushort* __restrict__ X,
                                              const float* __restrict__ cosT,
                                              const float* __restrict__ sinT,
                                              int nh, int estride, int rd) {
  int idx = blockIdx.x * 256 + threadIdx.x;
  int half = rd >> 1;
  int total = B_ * T_ * nh * half;
  if (idx >= total) return;
  int i = idx % half;
  int r2 = idx / half;
  int hh = r2 % nh;
  int row = r2 / nh;
  int t = row % T_;
  ushort* p = X + (size_t)row * estride + hh * HD_;
  float x0 = bf2f(p[i]), x1 = bf2f(p[i + half]);
  float c0 = cosT[t * rd + i], s0 = sinT[t * rd + i];
  float c1 = cosT[t * rd + i + half], s1 = sinT[t * rd + i + half];
  p[i] = f2bf(x0 * c0 - x1 * s0);
  p[i + half] = f2bf(x1 * c1 + x0 * s1);
}

// ---------------- flash attention (causal GQA) ----------------
__global__ __launch_bounds__(256) void attn_k(const ushort* __restrict__ Q,
                                              const ushort* __restrict__ Kt,
                                              const ushort* __restrict__ V,
                                              float* __restrict__ O) {
  __shared__ __align__(16) ushort P_lds[4][16][64];
  const int tid = threadIdx.x, w = tid >> 6, lane = tid & 63;
  const int l15 = lane & 15, l4 = lane >> 4;
  const int h = blockIdx.y, b = blockIdx.z, kv = h >> 2;
  const int qb = blockIdx.x;
  const int qbase = qb * 64 + w * 16;
  const float scale_ = 0.08838834764831845f;  // 1/sqrt(128)

  short8 qf[4];
#pragma unroll
  for (int kk = 0; kk < 4; kk++)
    qf[kk] = *(const short8*)&Q[(size_t)(b * T_ + qbase + l15) * EQ_ + h * HD_ + kk * 32 + l4 * 8];

  floatx4 acc_o[8];
#pragma unroll
  for (int nn = 0; nn < 8; nn++) acc_o[nn] = floatx4{0.f, 0.f, 0.f, 0.f};
  float mj[4] = {-1e30f, -1e30f, -1e30f, -1e30f};
  float lj[4] = {0.f, 0.f, 0.f, 0.f};

  const int kv_end = qb * 64 + 64;
  for (int kvb = 0; kvb < kv_end; kvb += 64) {
    floatx4 s[4];
#pragma unroll
    for (int n = 0; n < 4; n++) s[n] = floatx4{0.f, 0.f, 0.f, 0.f};
#pragma unroll
    for (int n = 0; n < 4; n++) {
#pragma unroll
      for (int kk = 0; kk < 4; kk++) {
        short8 kf = *(const short8*)&Kt[(size_t)(b * T_ + kvb + n * 16 + l15) * EKV_ + kv * HD_ + kk * 32 + l4 * 8];
        s[n] = __builtin_amdgcn_mfma_f32_16x16x32_bf16(qf[kk], kf, s[n], 0, 0, 0);
      }
    }
    // scale + causal mask + per-lane row max
    float pm[4] = {-1e30f, -1e30f, -1e30f, -1e30f};
#pragma unroll
    for (int n = 0; n < 4; n++)
#pragma unroll
      for (int j = 0; j < 4; j++) {
        float sv = s[n][j] * scale_;
        int col = kvb + n * 16 + l15;
        int row = qbase + l4 * 4 + j;
        sv = (col <= row) ? sv : -1e30f;
        s[n][j] = sv;
        pm[j] = fmaxf(pm[j], sv);
      }
#pragma unroll
    for (int j = 0; j < 4; j++) {
      pm[j] = fmaxf(pm[j], __shfl_xor(pm[j], 1));
      pm[j] = fmaxf(pm[j], __shfl_xor(pm[j], 2));
      pm[j] = fmaxf(pm[j], __shfl_xor(pm[j], 4));
      pm[j] = fmaxf(pm[j], __shfl_xor(pm[j], 8));
    }
    float ps[4] = {0.f, 0.f, 0.f, 0.f};
#pragma unroll
    for (int j = 0; j < 4; j++) {
      float mn = fmaxf(mj[j], pm[j]);
      float sc = __expf(mj[j] - mn);
      mj[j] = mn;
      lj[j] *= sc;
#pragma unroll
      for (int nn = 0; nn < 8; nn++) acc_o[nn][j] *= sc;
    }
#pragma unroll
    for (int n = 0; n < 4; n++)
#pragma unroll
      for (int j = 0; j < 4; j++) {
        float p = __expf(s[n][j] - mj[j]);
        ps[j] += p;
        P_lds[w][l4 * 4 + j][n * 16 + l15] = f2bf(p);
      }
#pragma unroll
    for (int j = 0; j < 4; j++) {
      ps[j] += __shfl_xor(ps[j], 1);
      ps[j] += __shfl_xor(ps[j], 2);
      ps[j] += __shfl_xor(ps[j], 4);
      ps[j] += __shfl_xor(ps[j], 8);
      lj[j] += ps[j];
    }
    __syncthreads();
#pragma unroll
    for (int kk = 0; kk < 2; kk++) {
      short8 pa = *(const short8*)&P_lds[w][l15][kk * 32 + l4 * 8];
#pragma unroll
      for (int n = 0; n < 8; n++) {
        short8 vf;
#pragma unroll
        for (int i = 0; i < 8; i++)
          vf[i] = (short)V[(size_t)(b * T_ + kvb + kk * 32 + l4 * 8 + i) * EKV_ + kv * HD_ + n * 16 + l15];
        acc_o[n] = __builtin_amdgcn_mfma_f32_16x16x32_bf16(pa, vf, acc_o[n], 0, 0, 0);
      }
    }
    __syncthreads();
  }
  // epilogue: normalize and store O[b][h][t][d] fp32
#pragma unroll
  for (int j = 0; j < 4; j++) {
    float inv = 1.f / lj[j];
#pragma unroll
    for (int n = 0; n < 8; n++)
      O[(size_t)((b * NH_ + h) * T_ + qbase + l4 * 4 + j) * HD_ + n * 16 + l15] = acc_o[n][j] * inv;
  }
}

// ---------------- XSA correction + layout to [b,t,e] bf16 ----------------
__global__ __launch_bounds__(256) void xsa_k(const float* __restrict__ O,
                                             const ushort* __restrict__ V,
                                             const int* __restrict__ flag,
                                             ushort* __restrict__ att) {
  int w = threadIdx.x >> 6, lane = threadIdx.x & 63;
  int idx = blockIdx.x * 4 + w;  // (b*NH + h)*T + t
  int t = idx % T_;
  int bh = idx / T_;
  int h = bh % NH_;
  int b = bh / NH_;
  const float* o = O + (size_t)idx * HD_;
  const ushort* v = V + (size_t)(b * T_ + t) * EKV_ + (h >> 2) * HD_;
  float o0 = o[lane], o1 = o[lane + 64];
  float v0 = bf2f(v[lane]), v1 = bf2f(v[lane + 64]);
  float dot = o0 * v0 + o1 * v1;
  float vns = v0 * v0 + v1 * v1;
  for (int m = 32; m; m >>= 1) {
    dot += __shfl_xor(dot, m);
    vns += __shfl_xor(vns, m);
  }
  if (*flag) {
    float f = dot / (vns + 1e-6f);
    o0 -= f * v0;
    o1 -= f * v1;
  }
  ushort* ap = att + (size_t)(b * T_ + t) * EQ_ + h * HD_;
  ap[lane] = f2bf(o0);
  ap[lane + 64] = f2bf(o1);
}

extern "C" void kernel_launch(void* const* d_in, const int* in_sizes, int n_in,
                              void* d_out, int out_size, void* d_ws, size_t ws_size,
                              hipStream_t stream) {
  const float* x    = (const float*)d_in[0];
  const float* cosT = (const float*)d_in[1];
  const float* sinT = (const float*)d_in[2];
  const float* wn   = (const float*)d_in[3];
  const float* wq   = (const float*)d_in[4];
  const float* wk   = (const float*)d_in[5];
  const float* wv   = (const float*)d_in[6];
  const float* wo   = (const float*)d_in[7];
  const int* use_xsa = (const int*)d_in[9];
  int rd = in_sizes[1] / T_;  // cos table is (T, rd)

  char* ws = (char*)d_ws;
  size_t off = 0;
  auto alloc = [&](size_t bytes) {
    char* p = ws + off;
    off += (bytes + 255) & ~(size_t)255;
    return p;
  };
  ushort* h_b  = (ushort*)alloc((size_t)B_ * T_ * D_ * 2);
  ushort* q_b  = (ushort*)alloc((size_t)B_ * T_ * EQ_ * 2);
  ushort* k_b  = (ushort*)alloc((size_t)B_ * T_ * EKV_ * 2);
  ushort* v_b  = (ushort*)alloc((size_t)B_ * T_ * EKV_ * 2);
  ushort* wq_b = (ushort*)alloc((size_t)EQ_ * D_ * 2);
  ushort* wk_b = (ushort*)alloc((size_t)EKV_ * D_ * 2);
  ushort* wv_b = (ushort*)alloc((size_t)EKV_ * D_ * 2);
  ushort* wo_b = (ushort*)alloc((size_t)D_ * EQ_ * 2);
  float*  o_f  = (float*)alloc((size_t)B_ * NH_ * T_ * HD_ * 4);
  ushort* att_b = h_b;  // reuse h region (dead after QKV GEMMs)

  cvt_k<<<EQ_ * D_ / 512, 256, 0, stream>>>(wq, wq_b, EQ_ * D_);
  cvt_k<<<EKV_ * D_ / 512, 256, 0, stream>>>(wk, wk_b, EKV_ * D_);
  cvt_k<<<EKV_ * D_ / 512, 256, 0, stream>>>(wv, wv_b, EKV_ * D_);
  cvt_k<<<D_ * EQ_ / 512, 256, 0, stream>>>(wo, wo_b, D_ * EQ_);
  rmsnorm_k<<<B_ * T_, 256, 0, stream>>>(x, wn, h_b);

  dim3 gq(EQ_ / 128, B_ * T_ / 128);
  gemm_bt<false><<<gq, 256, 0, stream>>>(h_b, wq_b, q_b, B_ * T_, EQ_, D_);
  dim3 gkv(EKV_ / 128, B_ * T_ / 128);
  gemm_bt<false><<<gkv, 256, 0, stream>>>(h_b, wk_b, k_b, B_ * T_, EKV_, D_);
  gemm_bt<false><<<gkv, 256, 0, stream>>>(h_b, wv_b, v_b, B_ * T_, EKV_, D_);

  int half = rd / 2;
  int totq = B_ * T_ * NH_ * half;
  rope_k<<<(totq + 255) / 256, 256, 0, stream>>>(q_b, cosT, sinT, NH_, EQ_, rd);
  int totk = B_ * T_ * NKV_ * half;
  rope_k<<<(totk + 255) / 256, 256, 0, stream>>>(k_b, cosT, sinT, NKV_, EKV_, rd);

  dim3 ga(T_ / 64, NH_, B_);
  attn_k<<<ga, 256, 0, stream>>>(q_b, k_b, v_b, o_f);

  xsa_k<<<B_ * NH_ * T_ / 4, 256, 0, stream>>>(o_f, v_b, use_xsa, att_b);

  dim3 go(D_ / 128, B_ * T_ / 128);
  gemm_bt<true><<<go, 256, 0, stream>>>(att_b, wo_b, d_out, B_ * T_, D_, D_);
}